// Round 1
// baseline (2630.065 us; speedup 1.0000x reference)
//
#include <hip/hip_runtime.h>
#include <math.h>

#define NH 8
#define D 64
#define BB 2
#define SS 2048

// ---------------- Stage 1: per-head projection + optional RoPE ----------------
// grid.x = B*NH*SS, block = 64. dst[b][h][s][d] = sum_z x[b][s][z] * W[h][z][d]
__global__ __launch_bounds__(64) void proj_rope_kernel(
    const float* __restrict__ x, const float* __restrict__ W,
    float* __restrict__ dst, int do_rope) {
    int idx = blockIdx.x;
    int s = idx % SS;
    int h = (idx / SS) % NH;
    int b = idx / (SS * NH);
    int d = threadIdx.x;

    __shared__ float xrow[D];
    xrow[d] = x[((size_t)b * SS + s) * D + d];
    __syncthreads();

    const float* Wp = W + (size_t)h * D * D + d;
    float acc = 0.f;
#pragma unroll
    for (int z = 0; z < D; ++z) acc += xrow[z] * Wp[(size_t)z * D];

    float outv = acc;
    if (do_rope) {
        int i = d >> 1;  // pair index
        float inv_freq = powf(10000.0f, -(float)(2 * i) / 64.0f);
        float angle = (float)s * inv_freq;
        float c = cosf(angle), sn = sinf(angle);
        float partner = __shfl_xor(acc, 1);
        if ((d & 1) == 0) outv = acc * c - partner * sn;   // even: x1*c - x2*s
        else              outv = partner * sn + acc * c;   // odd : x1*s + x2*c
    }
    dst[(((size_t)b * NH + h) * SS + s) * D + d] = outv;
}

// ---------------- Stage 2: per-row softmax stats (max, sum) over k<=q ----------
// grid.x = B*NH*SS (one wave per q-row), block = 64
__global__ __launch_bounds__(64) void rowstats_kernel(
    const float* __restrict__ qh, const float* __restrict__ kh,
    float* __restrict__ rowmax, float* __restrict__ rowsum) {
    int idx = blockIdx.x;            // (b*NH + h)*SS + q
    int q = idx % SS;
    int bh = idx / SS;
    int t = threadIdx.x;

    __shared__ float qrow[D];
    qrow[t] = qh[(size_t)idx * D + t];
    __syncthreads();

    const float* khp = kh + (size_t)bh * SS * D;
    float m = -3.0e38f, ssum = 0.f;
    for (int k = t; k <= q; k += 64) {
        const float* kr = khp + (size_t)k * D;
        float dot = 0.f;
#pragma unroll
        for (int dd = 0; dd < D; ++dd) dot += qrow[dd] * kr[dd];
        dot *= (1.0f / 64.0f);
        if (dot > m) { ssum = ssum * expf(m - dot) + 1.0f; m = dot; }
        else         { ssum += expf(dot - m); }
    }
    // wave combine of (m, ssum)
#pragma unroll
    for (int off = 1; off < 64; off <<= 1) {
        float m2 = __shfl_xor(m, off);
        float s2 = __shfl_xor(ssum, off);
        float M = fmaxf(m, m2);
        ssum = ssum * expf(m - M) + s2 * expf(m2 - M);
        m = M;
    }
    if (t == 0) { rowmax[idx] = m; rowsum[idx] = ssum; }
}

// ---------------- Stage 3: out[k,d] = sum_{q>k} P[q,k] * vh[q,d] ---------------
// grid.x = B*NH*SS (one wave per output position k), block = 64
__global__ __launch_bounds__(64) void av_kernel(
    const float* __restrict__ qh, const float* __restrict__ kh,
    const float* __restrict__ vh,
    const float* __restrict__ rowmax, const float* __restrict__ rowsum,
    float* __restrict__ att) {
    int idx = blockIdx.x;            // (b*NH + h)*SS + k
    int k = idx % SS;
    int bh = idx / SS;
    int h = bh % NH;
    int b = bh / NH;
    int t = threadIdx.x;

    __shared__ float krow[D];
    __shared__ float w[64];
    krow[t] = kh[(size_t)idx * D + t];
    __syncthreads();

    const float* qp = qh + (size_t)bh * SS * D;
    const float* vp = vh + (size_t)bh * SS * D;
    const float* rm = rowmax + (size_t)bh * SS;
    const float* rs = rowsum + (size_t)bh * SS;

    float acc = 0.f;
    for (int q0 = k + 1; q0 < SS; q0 += 64) {
        int q = q0 + t;
        float wv = 0.f;
        if (q < SS) {
            const float* qr = qp + (size_t)q * D;
            float dot = 0.f;
#pragma unroll
            for (int dd = 0; dd < D; ++dd) dot += qr[dd] * krow[dd];
            dot *= (1.0f / 64.0f);
            wv = expf(dot - rm[q]) / rs[q];
        }
        w[t] = wv;
        __syncthreads();
        int lim = min(64, SS - q0);
        for (int j = 0; j < lim; ++j)
            acc += w[j] * vp[(size_t)(q0 + j) * D + t];
        __syncthreads();
    }
    // att laid out as [b][k][h*64 + d] so stage 4 is a plain GEMM
    att[((size_t)b * SS + k) * (NH * D) + (size_t)h * D + t] = acc;
}

// ---------------- Stage 4: final projection: out = att(4096x512) @ W_o(512x64) -
// grid.x = B*SS, block = 64
__global__ __launch_bounds__(64) void outproj_kernel(
    const float* __restrict__ att, const float* __restrict__ Wo,
    float* __restrict__ out) {
    int idx = blockIdx.x;            // b*SS + s
    int t = threadIdx.x;
    __shared__ float row[NH * D];
    const float* ap = att + (size_t)idx * (NH * D);
    for (int z = t; z < NH * D; z += 64) row[z] = ap[z];
    __syncthreads();
    float acc = 0.f;
#pragma unroll 8
    for (int z = 0; z < NH * D; ++z) acc += row[z] * Wo[(size_t)z * D + t];
    out[(size_t)idx * D + t] = acc;
}

extern "C" void kernel_launch(void* const* d_in, const int* in_sizes, int n_in,
                              void* d_out, int out_size, void* d_ws, size_t ws_size,
                              hipStream_t stream) {
    const float* q  = (const float*)d_in[0];
    const float* k  = (const float*)d_in[1];
    const float* v  = (const float*)d_in[2];
    const float* Wq = (const float*)d_in[3];
    const float* Wk = (const float*)d_in[4];
    const float* Wv = (const float*)d_in[5];
    const float* Wo = (const float*)d_in[6];
    float* out = (float*)d_out;

    const size_t PROJ = (size_t)BB * NH * SS * D;   // 2,097,152 floats
    const size_t BHS  = (size_t)BB * NH * SS;       // 32,768

    float* ws   = (float*)d_ws;
    float* qh   = ws;
    float* kh   = qh + PROJ;
    float* vh   = kh + PROJ;
    float* rmax = vh + PROJ;
    float* rsum = rmax + BHS;
    float* att  = rsum + BHS;                       // PROJ floats

    dim3 blk(64);
    dim3 grid_proj(BB * NH * SS);

    proj_rope_kernel<<<grid_proj, blk, 0, stream>>>(q, Wq, qh, 1);
    proj_rope_kernel<<<grid_proj, blk, 0, stream>>>(k, Wk, kh, 1);
    proj_rope_kernel<<<grid_proj, blk, 0, stream>>>(v, Wv, vh, 0);

    rowstats_kernel<<<dim3(BB * NH * SS), blk, 0, stream>>>(qh, kh, rmax, rsum);

    av_kernel<<<dim3(BB * NH * SS), blk, 0, stream>>>(qh, kh, vh, rmax, rsum, att);

    outproj_kernel<<<dim3(BB * SS), blk, 0, stream>>>(att, Wo, out);
}